// Round 8
// baseline (261.293 us; speedup 1.0000x reference)
//
#include <hip/hip_runtime.h>
#include <stdint.h>

// Problem dims (fixed by reference)
#define M_ROWS 8192
#define K_DIM  4096
#define OUTD   144     // per-branch flat size (78 real + 66 imag)
#define PLANE  1179648 // complex elements per output (8192*144)
#define NT     32      // K_DIM / 128

typedef __attribute__((ext_vector_type(4))) float  float4v;
typedef __attribute__((ext_vector_type(8))) short  short8v;

static __device__ __forceinline__ unsigned short f2bf(float f) {
    // round-to-nearest-even fp32 -> bf16
    unsigned int u = __builtin_bit_cast(unsigned int, f);
    u += 0x7FFFu + ((u >> 16) & 1u);
    return (unsigned short)(u >> 16);
}

// ---------------------------------------------------------------------------
// Prep: Wt2 frag-major layout.
//   elem[( (w*32 + t)*4 + ks )*512 + q*128 + m*8 + e] =
//       bf16( W1[k][n] ), n = w*16+m (branch-split), k = t*128+ks*32+q*8+e.
// Wave w of the fused kernel then loads its B-fragment for (t,ks) as a
// single coalesced 1KB instruction: base + (w*32+t)*2048 + ks*512 + lane*8.
// ---------------------------------------------------------------------------
__global__ __launch_bounds__(256) void wt_kernel(
    const float* __restrict__ WC1, const float* __restrict__ WR1,
    unsigned short* __restrict__ Wt) {
    __shared__ float tile[64][65];
    const float* src = (blockIdx.y == 0) ? WC1 : WR1;
    const int k0 = blockIdx.x * 64;
    const int t = threadIdx.x;
    const int j = t & 63, qq = t >> 6;
#pragma unroll
    for (int p = 0; p < 16; ++p) {
        int i = p * 4 + qq;
        tile[i][j] = src[(size_t)(k0 + i) * 64 + j];   // tile[k'][n']
    }
    __syncthreads();
    const int tt  = blockIdx.x >> 1;        // k-tile (128-wide)
    const int ksb = (blockIdx.x & 1) * 2;   // ks base within tile
#pragma unroll
    for (int p = 0; p < 16; ++p) {
        int c = p * 256 + t;
        int e = c & 7, m = (c >> 3) & 15, q = (c >> 7) & 3;
        int ks_l = (c >> 9) & 1, w_l = (c >> 10) & 3;
        int kp = ks_l * 32 + q * 8 + e;               // k within 64-block
        int np = w_l * 16 + m;                        // n within 64-block
        int wg = blockIdx.y * 4 + w_l;                // global wave-col group
        size_t dst = ((size_t)(wg * 32 + tt) * 4 + (ksb + ks_l)) * 512
                   + q * 128 + m * 8 + e;
        Wt[dst] = f2bf(tile[kp][np]);
    }
}

// ---------------------------------------------------------------------------
// Fused kernel. Phase 1 = 16x4096 @ 4096x128 bf16 MFMA GEMM:
//  - B is WAVE-PRIVATE (wave w uses cols [16w,16w+16)) -> loaded global->REGS
//    from frag-major Wt2, fully coalesced, ZERO B LDS traffic.
//  - A (shared) staged in LDS frag-major: writes b128 @ lane*16 and reads
//    b128 @ ks*1024+lane*16 are both bank-conflict-free. Waves 0..3 stage.
//  - double-buffered A, 1 barrier per 128-k step; prefetch depth 1 tile,
//    waits are compiler-counted vmcnt (exact), manual lgkmcnt before barrier.
// Phases 2-5 unchanged. 512 threads; wave w owns output cols [16w,16w+16).
// Output bf16, IM-FIRST interleaved as before.
// ---------------------------------------------------------------------------

#define ISSUE_B(T_, B0_, B1_, B2_, B3_)                          \
    do { const unsigned short* bp_ = bpw + (size_t)(T_) * 2048;  \
         B0_ = *(const short8v*)(bp_ + 0 * 512);                 \
         B1_ = *(const short8v*)(bp_ + 1 * 512);                 \
         B2_ = *(const short8v*)(bp_ + 2 * 512);                 \
         B3_ = *(const short8v*)(bp_ + 3 * 512); } while (0)

#define ISSUE_A(T_, XL_, XH_)                                    \
    do { const float* ap_ = xpw + (size_t)(T_) * 128;            \
         XL_ = *(const float4*)(ap_);                            \
         XH_ = *(const float4*)(ap_ + 4); } while (0)

#define STORE_A(XL_, XH_, BUF_)                                        \
    do { short8v s_;                                                   \
         s_[0] = (short)f2bf((XL_).x); s_[1] = (short)f2bf((XL_).y);   \
         s_[2] = (short)f2bf((XL_).z); s_[3] = (short)f2bf((XL_).w);   \
         s_[4] = (short)f2bf((XH_).x); s_[5] = (short)f2bf((XH_).y);   \
         s_[6] = (short)f2bf((XH_).z); s_[7] = (short)f2bf((XH_).w);   \
         *(short8v*)(Asm_ + (BUF_) * 2048 + (w * 64 + lane) * 8) = s_; } while (0)

#define MFR(BUF_, B0_, B1_, B2_, B3_)                                          \
    do { const unsigned short* ab_ = Asm_ + (BUF_) * 2048 + lane * 8;          \
         short8v a0_ = *(const short8v*)(ab_ + 0 * 512);                       \
         short8v a1_ = *(const short8v*)(ab_ + 1 * 512);                       \
         short8v a2_ = *(const short8v*)(ab_ + 2 * 512);                       \
         short8v a3_ = *(const short8v*)(ab_ + 3 * 512);                       \
         acc = __builtin_amdgcn_mfma_f32_16x16x32_bf16(a0_, B0_, acc, 0, 0, 0);\
         acc = __builtin_amdgcn_mfma_f32_16x16x32_bf16(a1_, B1_, acc, 0, 0, 0);\
         acc = __builtin_amdgcn_mfma_f32_16x16x32_bf16(a2_, B2_, acc, 0, 0, 0);\
         acc = __builtin_amdgcn_mfma_f32_16x16x32_bf16(a3_, B3_, acc, 0, 0, 0);\
    } while (0)

__global__ __launch_bounds__(512, 4) void fused_kernel(
    const float* __restrict__ X, const unsigned short* __restrict__ Wt,
    const float* __restrict__ bC1, const float* __restrict__ bR1,
    const float* __restrict__ WC2, const float* __restrict__ bC2,
    const float* __restrict__ WR2, const float* __restrict__ bR2,
    const float* __restrict__ WC3, const float* __restrict__ bC3,
    const float* __restrict__ WR3, const float* __restrict__ bR3,
    unsigned short* __restrict__ OUT) {
    // LDS (41216 B):
    //  phase1: Asm [2][2048] u16 frag-major (8192 B)
    //  phase2: hs  [16][132] f32 (8448 B) | W2s [64][128] f32 (32768 B)
    //  phase3+: fl [16][288] f32 (18432 B) overlays W2s
    __shared__ __align__(16) char smem[41216];
    unsigned short* Asm_ = (unsigned short*)smem;          // [2][2048]
    float* hs  = (float*)smem;                             // [16][132]
    float* W2s = hs + 16 * 132;                            // [64][128]
    float* fl  = W2s;                                      // [16][288]

    const int tid  = threadIdx.x;       // 0..511
    const int lane = tid & 63;
    const int w    = tid >> 6;          // wave 0..7 -> col tile [16w, 16w+16)
    const int r0   = blockIdx.x * 16;
    const int m    = lane & 15, q = lane >> 4;

    float4v acc = {0.f, 0.f, 0.f, 0.f};

    // ---------------- Phase 1 ----------------------------------------------
    const unsigned short* bpw = Wt + (size_t)w * 32 * 2048 + lane * 8;
    // A staging (waves 0..3 only): wave v=w stages ks=v; lane -> row m,
    // k-offset q*8; loads 8 consecutive floats (rows tile X exactly).
    const float* xpw = X + (size_t)(r0 + m) * K_DIM + w * 32 + q * 8;
    const bool stager = (w < 4);

    short8v b00, b01, b02, b03, b10, b11, b12, b13;
    float4 xl0, xh0, xl1, xh1;

    ISSUE_B(0, b00, b01, b02, b03);
    if (stager) ISSUE_A(0, xl0, xh0);

#pragma unroll 1
    for (int t = 0; t < NT; t += 2) {
        // ---- even sub-iter: consume buf0/set0 ----
        if (stager) { STORE_A(xl0, xh0, 0); ISSUE_A(t + 1, xl1, xh1); }
        asm volatile("s_waitcnt lgkmcnt(0)" ::: "memory");
        __builtin_amdgcn_s_barrier();
        __builtin_amdgcn_sched_barrier(0);
        ISSUE_B(t + 1, b10, b11, b12, b13);
        MFR(0, b00, b01, b02, b03);
        // ---- odd sub-iter: consume buf1/set1 ----
        if (stager) {
            STORE_A(xl1, xh1, 1);
            if (t + 2 < NT) ISSUE_A(t + 2, xl0, xh0);
        }
        asm volatile("s_waitcnt lgkmcnt(0)" ::: "memory");
        __builtin_amdgcn_s_barrier();
        __builtin_amdgcn_sched_barrier(0);
        if (t + 2 < NT) ISSUE_B(t + 2, b00, b01, b02, b03);
        MFR(1, b10, b11, b12, b13);
    }
    __syncthreads();   // all MF readers done before smem is repurposed

    // Epilogue: C/D layout col=lane&15, row=quad*4+reg. Write h1 into hs.
    {
        const int c = w * 16 + m;
        const float bv = (c < 64) ? bC1[c] : bR1[c - 64];
#pragma unroll
        for (int i = 0; i < 4; ++i) {
            int r = q * 4 + i;
            float v = acc[i] + bv; v = v > 0.f ? v : 0.f;
            hs[r * 132 + c] = v;
        }
    }
    // Stage W2 = [WC2 | WR2] into LDS (64 x 128 f32), 2048 float4 / 512 thr.
#pragma unroll
    for (int p = 0; p < 4; ++p) {
        int fi = p * 512 + tid;
        int k = fi >> 5, c4 = fi & 31;
        int c = c4 * 4;
        const float* wsrc = (c < 64) ? (WC2 + (size_t)k * 64 + c)
                                     : (WR2 + (size_t)k * 64 + (c - 64));
        *(float4*)&W2s[k * 128 + c] = *(const float4*)wsrc;
    }
    __syncthreads();

    // ---------------- Phase 2: layer 2 (h2 = relu(h1 @ W2 + b2)) -----------
    const int rg = tid >> 5;          // 16 rows, 1 per row-group
    const int cg = tid & 31;          // 32 col quads
    const int koff2 = (cg < 16) ? 0 : 64;
    float acc2[4];
    {
        int c = cg * 4;
        const float* bsrc = (c < 64) ? (bC2 + c) : (bR2 + (c - 64));
#pragma unroll
        for (int j = 0; j < 4; ++j) acc2[j] = bsrc[j];
    }
    for (int k = 0; k < 64; ++k) {
        float4 wv = *(const float4*)&W2s[k * 128 + cg * 4];
        float a = hs[rg * 132 + koff2 + k];
        acc2[0] += a * wv.x; acc2[1] += a * wv.y;
        acc2[2] += a * wv.z; acc2[3] += a * wv.w;
    }
    float4 h2v;
    h2v.x = acc2[0] > 0.f ? acc2[0] : 0.f;
    h2v.y = acc2[1] > 0.f ? acc2[1] : 0.f;
    h2v.z = acc2[2] > 0.f ? acc2[2] : 0.f;
    h2v.w = acc2[3] > 0.f ? acc2[3] : 0.f;
    __syncthreads();                   // all reads of hs(h1)/W2s done
    *(float4*)&hs[rg * 132 + cg * 4] = h2v;   // hs now holds h2
    __syncthreads();

    // ---------------- Phase 3: layer 3 -> fl[16][288] (overlays W2s) -------
#pragma unroll 1
    for (int pass = 0; pass < 3; ++pass) {
        int c = pass * 128 + cg * 4;
        if (c < 288) {
            const int brn = (c >= 144);
            const int cl = c - (brn ? 144 : 0);
            const float* W3 = brn ? WR3 : WC3;
            const float* b3 = brn ? bR3 : bC3;
            const int ko = brn ? 64 : 0;
            float a3[4];
#pragma unroll
            for (int j = 0; j < 4; ++j) a3[j] = b3[cl + j];
            for (int k = 0; k < 64; ++k) {
                float4 wv = *(const float4*)(W3 + (size_t)k * OUTD + cl);
                float a = hs[rg * 132 + ko + k];
                a3[0] += a * wv.x; a3[1] += a * wv.y;
                a3[2] += a * wv.z; a3[3] += a * wv.w;
            }
            float4 v; v.x = a3[0]; v.y = a3[1]; v.z = a3[2]; v.w = a3[3];
            *(float4*)&fl[rg * 288 + c] = v;
        }
    }
    __syncthreads();

    // ---------------- Phase 4: softplus on the 12 diag reals per (row,brn) -
    if (tid < 384) {
        int r = tid / 24, rem = tid % 24;
        int brn = rem / 12, ii = rem % 12;
        float* f = &fl[r * 288 + brn * 144];
        int d = ii * (ii + 1) / 2 + ii;
        float xv = f[d];
        f[d] = (xv > 20.f) ? xv : log1pf(expf(xv));
    }
    __syncthreads();

    // ---------------- Phase 5: C = L L^H, Hermitian mirror, write OUT ------
    // IM-FIRST interleaved: one u32 = (re<<16)|im per complex element.
    unsigned int* O32 = (unsigned int*)OUT;
    for (int task = tid; task < 16 * 2 * 78; task += 512) {
        int r = task / 156, rem = task % 156;
        int brn = rem / 78, p = rem % 78;
        int i = 0;
        while (p >= (i + 1) * (i + 2) / 2) ++i;
        int j = p - i * (i + 1) / 2;              // j <= i
        const float* f = &fl[r * 288 + brn * 144]; // reals (diag softplus'd)
        const float* g = f + 78;                   // strict-lower imags
        const int ti = i * (i + 1) / 2, tj = j * (j + 1) / 2;
        const int si = i * (i - 1) / 2, sj = j * (j - 1) / 2;
        float re = 0.f, im = 0.f;
        for (int k = 0; k <= j; ++k) {
            float ar_ = f[ti + k];
            float ai  = (k == i) ? 0.f : g[si + k];
            float br_ = f[tj + k];
            float bi  = (k == j) ? 0.f : g[sj + k];
            re += ar_ * br_ + ai * bi;             // Re(L[i] . conj(L[j]))
            im += ai * br_ - ar_ * bi;             // Im
        }
        unsigned int reb = (unsigned int)f2bf(re);
        unsigned int imb = (unsigned int)f2bf(im);
        unsigned int imn = (unsigned int)f2bf(-im);
        size_t base = brn ? (size_t)PLANE : 0;     // in u32 units
        size_t q1 = (size_t)(r0 + r) * 144 + (size_t)(i * 12 + j);
        O32[base + q1] = imb | (reb << 16);        // imag low, real high
        if (i != j) {
            size_t q2 = (size_t)(r0 + r) * 144 + (size_t)(j * 12 + i);
            O32[base + q2] = imn | (reb << 16);
        }
    }
}

// ---------------------------------------------------------------------------
extern "C" void kernel_launch(void* const* d_in, const int* in_sizes, int n_in,
                              void* d_out, int out_size, void* d_ws, size_t ws_size,
                              hipStream_t stream) {
    const float* X   = (const float*)d_in[0];
    const float* WC1 = (const float*)d_in[1];
    const float* bC1 = (const float*)d_in[2];
    const float* WC2 = (const float*)d_in[3];
    const float* bC2 = (const float*)d_in[4];
    const float* WC3 = (const float*)d_in[5];
    const float* bC3 = (const float*)d_in[6];
    const float* WR1 = (const float*)d_in[7];
    const float* bR1 = (const float*)d_in[8];
    const float* WR2 = (const float*)d_in[9];
    const float* bR2 = (const float*)d_in[10];
    const float* WR3 = (const float*)d_in[11];
    const float* bR3 = (const float*)d_in[12];

    unsigned short* Wt = (unsigned short*)d_ws;   // 1 MB, frag-major Wt2
    unsigned short* OUT = (unsigned short*)d_out; // bf16, im-first interleaved

    wt_kernel<<<dim3(64, 2), 256, 0, stream>>>(WC1, WR1, Wt);
    fused_kernel<<<M_ROWS / 16, 512, 0, stream>>>(
        X, Wt, bC1, bR1, WC2, bC2, WR2, bR2, WC3, bC3, WR3, bR3, OUT);
}